// Round 4
// baseline (751.693 us; speedup 1.0000x reference)
//
#include <hip/hip_runtime.h>
#include <math.h>

// Problem constants (B,C,H,W) = (8,128,256,256), Ch = 64
constexpr int Bn = 8, Cn = 128, ChN = 64, Hn = 256, Wn = 256;
constexpr long long HWn  = (long long)Hn * Wn;   // 65536
constexpr long long CHWn = (long long)Cn * HWn;  // 8388608

// Pre-kernel: transpose w1 (64x128, o-major) -> w1t (128x64, c-major).
__global__ void prep_w1t(const float* __restrict__ w1, float* __restrict__ w1t) {
    int idx = blockIdx.x * blockDim.x + threadIdx.x;
    if (idx < ChN * Cn) {
        int o = idx >> 7;     // / 128
        int c = idx & 127;    // % 128
        w1t[c * ChN + o] = w1[idx];
    }
}

__device__ __forceinline__ float softplus_f(float x) {
    return fmaxf(x, 0.0f) + log1pf(expf(-fabsf(x)));
}

// 2 threads per pixel: tid&127 = pixel-in-block, tid>>7 = output-half.
// Per-thread working set: h[32] + x[8] + misc ~= 55 VGPR -> everything stays
// live (rounds 2-3 pathology: compiler fissioned h[64] loops and re-loaded
// the staged wi values from L1/L2, leaving the kernel latency-bound at
// VALUBusy~31%, HBM~29%).
constexpr int XS = 8;        // wi staging depth
constexpr int HO = 32;       // h outputs per thread

__global__ __launch_bounds__(256) void fused_lap(
    const float* __restrict__ u,
    const float* __restrict__ wi,
    const float* __restrict__ w1t,
    const float* __restrict__ b1,
    const float* __restrict__ w2,
    const float* __restrict__ b2,
    float* __restrict__ out)
{
    const int tid  = threadIdx.x;
    const int half = tid >> 7;           // 0 or 1
    const int px   = tid & 127;          // pixel within block
    const int p    = blockIdx.x * 128 + px;
    const int j = p & (Wn - 1);
    const int i = (p >> 8) & (Hn - 1);
    const int b = p >> 16;

    const size_t pixoff = (size_t)b * CHWn + (size_t)i * Wn + (size_t)j;

    // ---- phase 1: h[o] = sum_c wi[c] * w1[half*32+o][c] + b1[...] ----
    float h[HO];
    const float* bb1 = b1 + half * HO;
    #pragma unroll
    for (int o = 0; o < HO; ++o) h[o] = bb1[o];

    const float* wip  = wi + pixoff;
    const float* w1th = w1t + half * HO;          // row stride ChN
    for (int cc = 0; cc < Cn; cc += XS) {
        float x[XS];
        #pragma unroll
        for (int t = 0; t < XS; ++t)
            x[t] = wip[(size_t)(cc + t) * HWn];
        // Hard barrier: x[] must be materialized in VGPRs; re-loading is now
        // illegal, so any compiler rescheduling is register-only.
        #pragma unroll
        for (int t = 0; t < XS; ++t)
            asm volatile("" : "+v"(x[t]));
        #pragma unroll
        for (int t = 0; t < XS; ++t) {
            const float* wrow = w1th + (size_t)(cc + t) * ChN;
            #pragma unroll
            for (int o = 0; o < HO; ++o)
                h[o] = fmaf(wrow[o], x[t], h[o]);
        }
    }

    // ---- phase 2: partial dots over this thread's 32 h's, LDS pair-reduce ----
    float pk[4] = {0.f, 0.f, 0.f, 0.f};
    #pragma unroll
    for (int o = 0; o < HO; ++o) {
        float hv = fmaxf(h[o], 0.0f);
        #pragma unroll
        for (int k = 0; k < 4; ++k)
            pk[k] = fmaf(w2[k * ChN + half * HO + o], hv, pk[k]);
    }

    __shared__ float red[4][256];
    __shared__ float wdir[4][128];
    #pragma unroll
    for (int k = 0; k < 4; ++k) red[k][tid] = pk[k];
    __syncthreads();
    if (tid < 128) {
        #pragma unroll
        for (int k = 0; k < 4; ++k) {
            float a = red[k][tid] + red[k][tid + 128] + b2[k];
            wdir[k][tid] = softplus_f(a);
        }
    }
    __syncthreads();

    const float wu = wdir[0][px];   // up    -> u[i-1][j]
    const float wd = wdir[1][px];   // down  -> u[i+1][j]
    const float wl = wdir[2][px];   // left  -> u[i][j-1]
    const float wr = wdir[3][px];   // right -> u[i][j+1]
    const float wsum = (wu + wd) + (wl + wr);

    // ---- phase 3: this thread handles 64 channels of its pixel ----
    const float* up = u   + pixoff + (size_t)half * 64 * HWn;
    float*       op = out + pixoff + (size_t)half * 64 * HWn;
    const bool hu = (i > 0), hd = (i < Hn - 1), hl = (j > 0), hr = (j < Wn - 1);

    #pragma unroll 4
    for (int c = 0; c < 64; ++c) {
        const float* uc = up + (size_t)c * HWn;
        float uctr = uc[0];
        float uuu = hu ? uc[-Wn] : 0.0f;
        float uud = hd ? uc[ Wn] : 0.0f;
        float uul = hl ? uc[-1]  : 0.0f;
        float uur = hr ? uc[ 1]  : 0.0f;
        float lap = fmaf(wu, uuu,
                    fmaf(wd, uud,
                    fmaf(wl, uul,
                    fmaf(wr, uur, -wsum * uctr))));
        op[(size_t)c * HWn] = lap;
    }
}

extern "C" void kernel_launch(void* const* d_in, const int* in_sizes, int n_in,
                              void* d_out, int out_size, void* d_ws, size_t ws_size,
                              hipStream_t stream) {
    const float* u  = (const float*)d_in[0];
    const float* wi = (const float*)d_in[1];
    const float* w1 = (const float*)d_in[2];
    const float* b1 = (const float*)d_in[3];
    const float* w2 = (const float*)d_in[4];
    const float* b2 = (const float*)d_in[5];
    float* out = (float*)d_out;
    float* w1t = (float*)d_ws;   // 8192 floats = 32 KB

    prep_w1t<<<(ChN * Cn + 255) / 256, 256, 0, stream>>>(w1, w1t);

    int nblocks = Bn * Hn * Wn / 128;   // 4096 blocks, 2 threads/pixel
    fused_lap<<<nblocks, 256, 0, stream>>>(u, wi, w1t, b1, w2, b2, out);
}

// Round 5
// 291.920 us; speedup vs baseline: 2.5750x; 2.5750x over previous
//
#include <hip/hip_runtime.h>
#include <math.h>

// Problem constants (B,C,H,W) = (8,128,256,256), Ch = 64
constexpr int Bn = 8, Cn = 128, ChN = 64, Hn = 256, Wn = 256;
constexpr long long HWn  = (long long)Hn * Wn;   // 65536
constexpr long long CHWn = (long long)Cn * HWn;  // 8388608

typedef short  s16x8  __attribute__((ext_vector_type(8)));
typedef __bf16 bf16x8 __attribute__((ext_vector_type(8)));
typedef float  f32x4  __attribute__((ext_vector_type(4)));

static __device__ __forceinline__ unsigned short f2bf(float f) {
    union { float f; unsigned u; } v; v.f = f;
    unsigned r = (v.u + 0x7FFFu + ((v.u >> 16) & 1u)) >> 16;
    return (unsigned short)r;
}
static __device__ __forceinline__ bf16x8 tobf(s16x8 s) {
    bf16x8 r; __builtin_memcpy(&r, &s, 16); return r;
}

// Prep: pack w1 (64x128 f32) into MFMA A-fragments.
// A-frag layout for mfma_f32_16x16x32_bf16: lane holds A[row=lane&15][k=(lane>>4)*8 + t],
// t=0..7 contiguous -> 8 contiguous bf16 from w1 row (o-tile ot, k-block kb).
// af[(ot*4+kb)*64 + lane] = packed 8 bf16 (uint4).
// Also: w2t[o*4+k] = w2[k][o] (float4-readable per o).
__global__ void prep(const float* __restrict__ w1, const float* __restrict__ w2,
                     uint4* __restrict__ af, float* __restrict__ w2t) {
    int idx = blockIdx.x * 256 + threadIdx.x;
    if (idx < 1024) {
        int lane = idx & 63, kb = (idx >> 6) & 3, ot = idx >> 8;
        int row   = ot * 16 + (lane & 15);
        int kbase = kb * 32 + ((lane >> 4) & 3) * 8;
        const float* src = w1 + row * Cn + kbase;
        unsigned short b[8];
        #pragma unroll
        for (int t = 0; t < 8; ++t) b[t] = f2bf(src[t]);
        uint4 r;
        r.x = (unsigned)b[0] | ((unsigned)b[1] << 16);
        r.y = (unsigned)b[2] | ((unsigned)b[3] << 16);
        r.z = (unsigned)b[4] | ((unsigned)b[5] << 16);
        r.w = (unsigned)b[6] | ((unsigned)b[7] << 16);
        af[idx] = r;
    } else if (idx < 1024 + ChN * 4) {
        int t = idx - 1024;               // t = o*4 + k
        w2t[t] = w2[(t & 3) * ChN + (t >> 2)];
    }
}

__device__ __forceinline__ float softplus_f(float x) {
    return fmaxf(x, 0.0f) + log1pf(expf(-fabsf(x)));
}

// Block = 256 threads = 4 waves; block covers one (b,i) row of 256 pixels.
// Wave wv covers pixels j in [wv*64, wv*64+64): phase 1/2 in 4 chunks of 16
// (MFMA 16x16x32, M=o, N=pixel), phase 3 one lane per pixel, fully coalesced.
__global__ __launch_bounds__(256, 4) void fused_lap(
    const float* __restrict__ u,
    const float* __restrict__ wi,
    const uint4* __restrict__ af,
    const float* __restrict__ w2t,
    const float* __restrict__ b1,
    const float* __restrict__ b2,
    float* __restrict__ out)
{
    const int tid  = threadIdx.x;
    const int wv   = tid >> 6;
    const int lane = tid & 63;
    const int l15  = lane & 15;
    const int lg   = lane >> 4;          // lane group 0..3

    const int pbase = blockIdx.x * 256;  // row-aligned: j = wv*64 + ...
    const int i = (pbase >> 8) & (Hn - 1);
    const int b =  pbase >> 16;
    const bool hu = (i > 0), hd = (i < Hn - 1);
    const size_t rowoff = (size_t)b * CHWn + (size_t)i * Wn;

    const float bb2_0 = b2[0], bb2_1 = b2[1], bb2_2 = b2[2], bb2_3 = b2[3];

    float wu_c[4], wd_c[4], wl_c[4], wr_c[4];

    #pragma unroll
    for (int chunk = 0; chunk < 4; ++chunk) {
        const int j0 = wv * 64 + chunk * 16;

        // ---- phase 1: D[o][px] = w1 · wi  (16 px, 64 o, K=128) ----
        f32x4 acc[4];
        #pragma unroll
        for (int ot = 0; ot < 4; ++ot) acc[ot] = (f32x4){0.f, 0.f, 0.f, 0.f};

        const float* wip = wi + rowoff + j0 + l15;
        #pragma unroll
        for (int kb = 0; kb < 4; ++kb) {
            // B-frag: lane holds wi[k=(kb*32+lg*8+t)][px=l15]
            float xb[8];
            #pragma unroll
            for (int t = 0; t < 8; ++t)
                xb[t] = wip[(size_t)(kb * 32 + lg * 8 + t) * HWn];
            s16x8 bs;
            #pragma unroll
            for (int t = 0; t < 8; ++t) bs[t] = (short)f2bf(xb[t]);
            bf16x8 bfrag = tobf(bs);
            #pragma unroll
            for (int ot = 0; ot < 4; ++ot) {
                s16x8 as = ((const s16x8*)af)[(ot * 4 + kb) * 64 + lane];
                acc[ot] = __builtin_amdgcn_mfma_f32_16x16x32_bf16(
                              tobf(as), bfrag, acc[ot], 0, 0, 0);
            }
        }

        // ---- phase 2: lane holds h[o = ot*16 + lg*4 + r] for pixel (j0+l15) ----
        float a0 = 0.f, a1 = 0.f, a2 = 0.f, a3 = 0.f;
        #pragma unroll
        for (int ot = 0; ot < 4; ++ot) {
            #pragma unroll
            for (int r = 0; r < 4; ++r) {
                int o = ot * 16 + lg * 4 + r;
                float hv = fmaxf(acc[ot][r] + b1[o], 0.f);
                const float4 wv4 = ((const float4*)w2t)[o];
                a0 = fmaf(wv4.x, hv, a0);
                a1 = fmaf(wv4.y, hv, a1);
                a2 = fmaf(wv4.z, hv, a2);
                a3 = fmaf(wv4.w, hv, a3);
            }
        }
        // reduce across the 4 lane groups (each ends with the full dot)
        a0 += __shfl_xor(a0, 16); a0 += __shfl_xor(a0, 32);
        a1 += __shfl_xor(a1, 16); a1 += __shfl_xor(a1, 32);
        a2 += __shfl_xor(a2, 16); a2 += __shfl_xor(a2, 32);
        a3 += __shfl_xor(a3, 16); a3 += __shfl_xor(a3, 32);

        wu_c[chunk] = softplus_f(a0 + bb2_0);
        wd_c[chunk] = softplus_f(a1 + bb2_1);
        wl_c[chunk] = softplus_f(a2 + bb2_2);
        wr_c[chunk] = softplus_f(a3 + bb2_3);
    }

    // Lane L holds (for every chunk) the w-dirs of pixel chunk*16 + l15.
    // Its phase-3 pixel is j = wv*64 + lane = wv*64 + lg*16 + l15 -> chunk = lg.
    const float wu = lg == 0 ? wu_c[0] : lg == 1 ? wu_c[1] : lg == 2 ? wu_c[2] : wu_c[3];
    const float wd = lg == 0 ? wd_c[0] : lg == 1 ? wd_c[1] : lg == 2 ? wd_c[2] : wd_c[3];
    const float wl = lg == 0 ? wl_c[0] : lg == 1 ? wl_c[1] : lg == 2 ? wl_c[2] : wl_c[3];
    const float wr = lg == 0 ? wr_c[0] : lg == 1 ? wr_c[1] : lg == 2 ? wr_c[2] : wr_c[3];
    const float wsum = (wu + wd) + (wl + wr);

    // ---- phase 3: one lane per pixel, 64-lane contiguous streaming ----
    const int   j   = wv * 64 + lane;
    const size_t pix = rowoff + j;
    const bool hl = (j > 0), hr = (j < Wn - 1);
    const float* up_ = u   + pix;
    float*       op  = out + pix;

    #pragma unroll 4
    for (int c = 0; c < Cn; ++c) {
        const float* uc = up_ + (size_t)c * HWn;
        float uctr = uc[0];
        float uuu = hu ? uc[-Wn] : 0.0f;
        float uud = hd ? uc[ Wn] : 0.0f;
        float uul = hl ? uc[-1]  : 0.0f;
        float uur = hr ? uc[ 1]  : 0.0f;
        float lap = fmaf(wu, uuu,
                    fmaf(wd, uud,
                    fmaf(wl, uul,
                    fmaf(wr, uur, -wsum * uctr))));
        op[(size_t)c * HWn] = lap;
    }
}

extern "C" void kernel_launch(void* const* d_in, const int* in_sizes, int n_in,
                              void* d_out, int out_size, void* d_ws, size_t ws_size,
                              hipStream_t stream) {
    const float* u  = (const float*)d_in[0];
    const float* wi = (const float*)d_in[1];
    const float* w1 = (const float*)d_in[2];
    const float* b1 = (const float*)d_in[3];
    const float* w2 = (const float*)d_in[4];
    const float* b2 = (const float*)d_in[5];
    float* out = (float*)d_out;

    uint4* af  = (uint4*)d_ws;                       // 1024 * 16B = 16 KB
    float* w2t = (float*)((char*)d_ws + 16384);      // 256 * 4B  = 1 KB

    prep<<<5, 256, 0, stream>>>(w1, w2, af, w2t);

    int nblocks = Bn * Hn * Wn / 256;                // 2048: one row each
    fused_lap<<<nblocks, 256, 0, stream>>>(u, wi, af, w2t, b1, b2, out);
}

// Round 7
// 253.235 us; speedup vs baseline: 2.9684x; 1.1528x over previous
//
#include <hip/hip_runtime.h>
#include <math.h>

// Problem constants (B,C,H,W) = (8,128,256,256), Ch = 64
constexpr int Bn = 8, Cn = 128, ChN = 64, Hn = 256, Wn = 256;
constexpr long long HWn  = (long long)Hn * Wn;   // 65536
constexpr long long CHWn = (long long)Cn * HWn;  // 8388608

typedef short  s16x8  __attribute__((ext_vector_type(8)));
typedef __bf16 bf16x8 __attribute__((ext_vector_type(8)));
typedef float  f32x4  __attribute__((ext_vector_type(4)));

static __device__ __forceinline__ unsigned short f2bf(float f) {
    union { float f; unsigned u; } v; v.f = f;
    unsigned r = (v.u + 0x7FFFu + ((v.u >> 16) & 1u)) >> 16;
    return (unsigned short)r;
}
static __device__ __forceinline__ bf16x8 tobf(s16x8 s) {
    bf16x8 r; __builtin_memcpy(&r, &s, 16); return r;
}

// Prep: pack w1 (64x128 f32) into MFMA A-fragments (bf16), and transpose w2.
__global__ void prep(const float* __restrict__ w1, const float* __restrict__ w2,
                     uint4* __restrict__ af, float* __restrict__ w2t) {
    int idx = blockIdx.x * 256 + threadIdx.x;
    if (idx < 1024) {
        int lane = idx & 63, kb = (idx >> 6) & 3, ot = idx >> 8;
        int row   = ot * 16 + (lane & 15);
        int kbase = kb * 32 + ((lane >> 4) & 3) * 8;
        const float* src = w1 + row * Cn + kbase;
        unsigned short b[8];
        #pragma unroll
        for (int t = 0; t < 8; ++t) b[t] = f2bf(src[t]);
        uint4 r;
        r.x = (unsigned)b[0] | ((unsigned)b[1] << 16);
        r.y = (unsigned)b[2] | ((unsigned)b[3] << 16);
        r.z = (unsigned)b[4] | ((unsigned)b[5] << 16);
        r.w = (unsigned)b[6] | ((unsigned)b[7] << 16);
        af[idx] = r;
    } else if (idx < 1024 + ChN * 4) {
        int t = idx - 1024;               // t = o*4 + k
        w2t[t] = w2[(t & 3) * ChN + (t >> 2)];
    }
}

__device__ __forceinline__ float softplus_f(float x) {
    return fmaxf(x, 0.0f) + log1pf(expf(-fabsf(x)));
}

// Block = 256 threads = 4 waves. Each wave owns one full image row (256 px).
// Grid = 2048 rows / 4 = 512 blocks, XCD-bijective swizzled (64 blocks/XCD)
// so rows i-1,i,i+1 live on the same XCD's L2.
// Phase 1/2: MFMA 16x16x32 over 16 px-chunks; phase 3: float4 streaming,
// 4 px/lane, left/right from registers+shfl, up/down via +-1024B imm offsets.
__global__ __launch_bounds__(256) void fused_lap(
    const float* __restrict__ u,
    const float* __restrict__ wi,
    const uint4* __restrict__ af,
    const float* __restrict__ w2t,
    const float* __restrict__ b1,
    const float* __restrict__ b2,
    float* __restrict__ out)
{
    const int tid  = threadIdx.x;
    const int wv   = tid >> 6;
    const int lane = tid & 63;
    const int l15  = lane & 15;
    const int lg   = lane >> 4;          // lane group 0..3

    // 512 blocks, 8 XCDs -> 64 contiguous row-groups per XCD
    const int swz = (blockIdx.x & 7) * 64 + (blockIdx.x >> 3);
    const int R   = swz * 4 + wv;        // global row id 0..2047
    const int i   = R & (Hn - 1);
    const int b   = R >> 8;
    const bool hu = (i > 0), hd = (i < Hn - 1);
    const size_t rowoff = (size_t)b * CHWn + (size_t)i * Wn;

    __shared__ float wlds[4][4][256];    // [dir][wave][swizzled px]

    const float bb2_0 = b2[0], bb2_1 = b2[1], bb2_2 = b2[2], bb2_3 = b2[3];

    // b1 folded into MFMA C-init: lane's C rows are o = ot*16 + lg*4 + r
    f32x4 b1f[4];
    #pragma unroll
    for (int ot = 0; ot < 4; ++ot)
        b1f[ot] = *(const f32x4*)(b1 + ot * 16 + lg * 4);

    // ---- phases 1+2: 16 chunks of 16 px ----
    #pragma unroll 2
    for (int ch = 0; ch < 16; ++ch) {
        const int j0 = ch * 16;
        f32x4 acc[4];
        #pragma unroll
        for (int ot = 0; ot < 4; ++ot) acc[ot] = b1f[ot];

        const float* wip = wi + rowoff + j0 + l15;
        #pragma unroll
        for (int kb = 0; kb < 4; ++kb) {
            float xb[8];
            #pragma unroll
            for (int t = 0; t < 8; ++t)
                xb[t] = wip[(size_t)(kb * 32 + lg * 8 + t) * HWn];
            s16x8 bs;
            #pragma unroll
            for (int t = 0; t < 8; ++t) bs[t] = (short)f2bf(xb[t]);
            bf16x8 bfrag = tobf(bs);
            #pragma unroll
            for (int ot = 0; ot < 4; ++ot) {
                s16x8 as = ((const s16x8*)af)[(ot * 4 + kb) * 64 + lane];
                acc[ot] = __builtin_amdgcn_mfma_f32_16x16x32_bf16(
                              tobf(as), bfrag, acc[ot], 0, 0, 0);
            }
        }

        // phase 2: lane holds h[o=ot*16+lg*4+r] (b1 already added) for px j0+l15
        float a0 = 0.f, a1 = 0.f, a2 = 0.f, a3 = 0.f;
        #pragma unroll
        for (int ot = 0; ot < 4; ++ot) {
            #pragma unroll
            for (int r = 0; r < 4; ++r) {
                int o = ot * 16 + lg * 4 + r;
                float hv = fmaxf(acc[ot][r], 0.f);
                const float4 w4 = ((const float4*)w2t)[o];
                a0 = fmaf(w4.x, hv, a0);
                a1 = fmaf(w4.y, hv, a1);
                a2 = fmaf(w4.z, hv, a2);
                a3 = fmaf(w4.w, hv, a3);
            }
        }
        a0 += __shfl_xor(a0, 16); a0 += __shfl_xor(a0, 32);
        a1 += __shfl_xor(a1, 16); a1 += __shfl_xor(a1, 32);
        a2 += __shfl_xor(a2, 16); a2 += __shfl_xor(a2, 32);
        a3 += __shfl_xor(a3, 16); a3 += __shfl_xor(a3, 32);

        if (lg == 0) {
            // write swizzled so the float4-per-lane read below is linear-in-lane
            // px = j0 + l15; pxs = (px>>2) + 64*(px&3)
            int pxs = 4 * ch + (l15 >> 2) + 64 * (l15 & 3);
            wlds[0][wv][pxs] = softplus_f(a0 + bb2_0);
            wlds[1][wv][pxs] = softplus_f(a1 + bb2_1);
            wlds[2][wv][pxs] = softplus_f(a2 + bb2_2);
            wlds[3][wv][pxs] = softplus_f(a3 + bb2_3);
        }
    }

    // Same-wave LDS write->read (lockstep, DS pipe in program order): no barrier.
    // Lane L needs px 4L..4L+3; elem e lives at [d][wv][64*e + L] (conflict-free).
    float4 WU, WD, WL, WR;
    WU.x = wlds[0][wv][lane];       WU.y = wlds[0][wv][64 + lane];
    WU.z = wlds[0][wv][128 + lane]; WU.w = wlds[0][wv][192 + lane];
    WD.x = wlds[1][wv][lane];       WD.y = wlds[1][wv][64 + lane];
    WD.z = wlds[1][wv][128 + lane]; WD.w = wlds[1][wv][192 + lane];
    WL.x = wlds[2][wv][lane];       WL.y = wlds[2][wv][64 + lane];
    WL.z = wlds[2][wv][128 + lane]; WL.w = wlds[2][wv][192 + lane];
    WR.x = wlds[3][wv][lane];       WR.y = wlds[3][wv][64 + lane];
    WR.z = wlds[3][wv][128 + lane]; WR.w = wlds[3][wv][192 + lane];
    float4 WS;
    WS.x = (WU.x + WD.x) + (WL.x + WR.x);
    WS.y = (WU.y + WD.y) + (WL.y + WR.y);
    WS.z = (WU.z + WD.z) + (WL.z + WR.z);
    WS.w = (WU.w + WD.w) + (WL.w + WR.w);

    // ---- phase 3: float4 per lane, 3 loads + 1 store per channel ----
    const int j4 = lane * 4;
    const float* pc = u   + rowoff + j4;
    float*       po = out + rowoff + j4;

    if (hu && hd) {
        #pragma unroll 4
        for (int c = 0; c < Cn; ++c) {
            const float* rp = pc + (size_t)c * HWn;
            float4 ctr = *(const float4*)rp;
            float4 up4 = *(const float4*)(rp - Wn);
            float4 dn4 = *(const float4*)(rp + Wn);
            float lw = __shfl(ctr.w, lane - 1);
            float rw = __shfl(ctr.x, lane + 1);
            float lfx = (lane == 0)  ? 0.f : lw;
            float rtw = (lane == 63) ? 0.f : rw;
            float4 r;
            r.x = fmaf(WU.x, up4.x, fmaf(WD.x, dn4.x, fmaf(WL.x, lfx,   fmaf(WR.x, ctr.y, -WS.x * ctr.x))));
            r.y = fmaf(WU.y, up4.y, fmaf(WD.y, dn4.y, fmaf(WL.y, ctr.x, fmaf(WR.y, ctr.z, -WS.y * ctr.y))));
            r.z = fmaf(WU.z, up4.z, fmaf(WD.z, dn4.z, fmaf(WL.z, ctr.y, fmaf(WR.z, ctr.w, -WS.z * ctr.z))));
            r.w = fmaf(WU.w, up4.w, fmaf(WD.w, dn4.w, fmaf(WL.w, ctr.z, fmaf(WR.w, rtw,   -WS.w * ctr.w))));
            *(float4*)(po + (size_t)c * HWn) = r;
        }
    } else {
        const float4 z4 = {0.f, 0.f, 0.f, 0.f};
        #pragma unroll 4
        for (int c = 0; c < Cn; ++c) {
            const float* rp = pc + (size_t)c * HWn;
            float4 ctr = *(const float4*)rp;
            float4 up4 = hu ? *(const float4*)(rp - Wn) : z4;
            float4 dn4 = hd ? *(const float4*)(rp + Wn) : z4;
            float lw = __shfl(ctr.w, lane - 1);
            float rw = __shfl(ctr.x, lane + 1);
            float lfx = (lane == 0)  ? 0.f : lw;
            float rtw = (lane == 63) ? 0.f : rw;
            float4 r;
            r.x = fmaf(WU.x, up4.x, fmaf(WD.x, dn4.x, fmaf(WL.x, lfx,   fmaf(WR.x, ctr.y, -WS.x * ctr.x))));
            r.y = fmaf(WU.y, up4.y, fmaf(WD.y, dn4.y, fmaf(WL.y, ctr.x, fmaf(WR.y, ctr.z, -WS.y * ctr.y))));
            r.z = fmaf(WU.z, up4.z, fmaf(WD.z, dn4.z, fmaf(WL.z, ctr.y, fmaf(WR.z, ctr.w, -WS.z * ctr.z))));
            r.w = fmaf(WU.w, up4.w, fmaf(WD.w, dn4.w, fmaf(WL.w, ctr.z, fmaf(WR.w, rtw,   -WS.w * ctr.w))));
            *(float4*)(po + (size_t)c * HWn) = r;
        }
    }
}

extern "C" void kernel_launch(void* const* d_in, const int* in_sizes, int n_in,
                              void* d_out, int out_size, void* d_ws, size_t ws_size,
                              hipStream_t stream) {
    const float* u  = (const float*)d_in[0];
    const float* wi = (const float*)d_in[1];
    const float* w1 = (const float*)d_in[2];
    const float* b1 = (const float*)d_in[3];
    const float* w2 = (const float*)d_in[4];
    const float* b2 = (const float*)d_in[5];
    float* out = (float*)d_out;

    uint4* af  = (uint4*)d_ws;                       // 1024 * 16B = 16 KB
    float* w2t = (float*)((char*)d_ws + 16384);      // 256 * 4B  = 1 KB

    prep<<<5, 256, 0, stream>>>(w1, w2, af, w2t);

    int nblocks = Bn * Hn / 4;                       // 512 blocks, 4 rows each
    fused_lap<<<nblocks, 256, 0, stream>>>(u, wi, af, w2t, b1, b2, out);
}

// Round 8
// 222.228 us; speedup vs baseline: 3.3825x; 1.1395x over previous
//
#include <hip/hip_runtime.h>
#include <math.h>

// Problem constants (B,C,H,W) = (8,128,256,256), Ch = 64
constexpr int Bn = 8, Cn = 128, ChN = 64, Hn = 256, Wn = 256;
constexpr long long HWn  = (long long)Hn * Wn;   // 65536
constexpr long long CHWn = (long long)Cn * HWn;  // 8388608

typedef short  s16x8  __attribute__((ext_vector_type(8)));
typedef __bf16 bf16x8 __attribute__((ext_vector_type(8)));
typedef float  f32x4  __attribute__((ext_vector_type(4)));

static __device__ __forceinline__ unsigned short f2bf(float f) {
    union { float f; unsigned u; } v; v.f = f;
    unsigned r = (v.u + 0x7FFFu + ((v.u >> 16) & 1u)) >> 16;
    return (unsigned short)r;
}
static __device__ __forceinline__ bf16x8 tobf(s16x8 s) {
    bf16x8 r; __builtin_memcpy(&r, &s, 16); return r;
}

// Prep: pack w1 (64x128 f32) into MFMA A-fragments (bf16), and transpose w2.
__global__ void prep(const float* __restrict__ w1, const float* __restrict__ w2,
                     uint4* __restrict__ af, float* __restrict__ w2t) {
    int idx = blockIdx.x * 256 + threadIdx.x;
    if (idx < 1024) {
        int lane = idx & 63, kb = (idx >> 6) & 3, ot = idx >> 8;
        int row   = ot * 16 + (lane & 15);
        int kbase = kb * 32 + ((lane >> 4) & 3) * 8;
        const float* src = w1 + row * Cn + kbase;
        unsigned short b[8];
        #pragma unroll
        for (int t = 0; t < 8; ++t) b[t] = f2bf(src[t]);
        uint4 r;
        r.x = (unsigned)b[0] | ((unsigned)b[1] << 16);
        r.y = (unsigned)b[2] | ((unsigned)b[3] << 16);
        r.z = (unsigned)b[4] | ((unsigned)b[5] << 16);
        r.w = (unsigned)b[6] | ((unsigned)b[7] << 16);
        af[idx] = r;
    } else if (idx < 1024 + ChN * 4) {
        int t = idx - 1024;               // t = o*4 + k
        w2t[t] = w2[(t & 3) * ChN + (t >> 2)];
    }
}

__device__ __forceinline__ float softplus_f(float x) {
    return fmaxf(x, 0.0f) + log1pf(expf(-fabsf(x)));
}

// Block = 256 threads = 4 waves; block owns ONE image row (256 px).
// Round-7 pathology: 512 blocks -> 2 waves/SIMD, occupancy 18%, latency-bound.
// Now: phase 1/2 chunks split across the 4 waves (4 each, LDS-shared w-dirs),
// phase 3 splits 128 channels across waves (32 each). Grid = 2048 blocks.
__global__ __launch_bounds__(256) void fused_lap(
    const float* __restrict__ u,
    const float* __restrict__ wi,
    const uint4* __restrict__ af,
    const float* __restrict__ w2t,
    const float* __restrict__ b1,
    const float* __restrict__ b2,
    float* __restrict__ out)
{
    const int tid  = threadIdx.x;
    const int wv   = tid >> 6;
    const int lane = tid & 63;
    const int l15  = lane & 15;
    const int lg   = lane >> 4;          // lane group 0..3

    // 2048 blocks, 8 XCDs -> 256 contiguous rows per XCD (rows i-1,i,i+1 same L2)
    const int R = (blockIdx.x & 7) * 256 + (blockIdx.x >> 3);   // row id 0..2047
    const int i = R & (Hn - 1);
    const int b = R >> 8;
    const bool hu = (i > 0), hd = (i < Hn - 1);
    const size_t rowoff = (size_t)b * CHWn + (size_t)i * Wn;

    __shared__ float wlds[4][256];       // [dir][swizzled px] for the whole row

    const float bb2_0 = b2[0], bb2_1 = b2[1], bb2_2 = b2[2], bb2_3 = b2[3];

    // b1 folded into MFMA C-init: lane's C rows are o = ot*16 + lg*4 + r
    f32x4 b1f[4];
    #pragma unroll
    for (int ot = 0; ot < 4; ++ot)
        b1f[ot] = *(const f32x4*)(b1 + ot * 16 + lg * 4);

    // ---- phases 1+2: wave wv handles 4 of the 16 px-chunks ----
    #pragma unroll
    for (int cc = 0; cc < 4; ++cc) {
        const int ch = wv * 4 + cc;
        const int j0 = ch * 16;
        f32x4 acc[4];
        #pragma unroll
        for (int ot = 0; ot < 4; ++ot) acc[ot] = b1f[ot];

        const float* wip = wi + rowoff + j0 + l15;
        #pragma unroll
        for (int kb = 0; kb < 4; ++kb) {
            float xb[8];
            #pragma unroll
            for (int t = 0; t < 8; ++t)
                xb[t] = wip[(size_t)(kb * 32 + lg * 8 + t) * HWn];
            s16x8 bs;
            #pragma unroll
            for (int t = 0; t < 8; ++t) bs[t] = (short)f2bf(xb[t]);
            bf16x8 bfrag = tobf(bs);
            #pragma unroll
            for (int ot = 0; ot < 4; ++ot) {
                s16x8 as = ((const s16x8*)af)[(ot * 4 + kb) * 64 + lane];
                acc[ot] = __builtin_amdgcn_mfma_f32_16x16x32_bf16(
                              tobf(as), bfrag, acc[ot], 0, 0, 0);
            }
        }

        // phase 2: lane holds h[o=ot*16+lg*4+r] (b1 added) for px j0+l15
        float a0 = 0.f, a1 = 0.f, a2 = 0.f, a3 = 0.f;
        #pragma unroll
        for (int ot = 0; ot < 4; ++ot) {
            #pragma unroll
            for (int r = 0; r < 4; ++r) {
                int o = ot * 16 + lg * 4 + r;
                float hv = fmaxf(acc[ot][r], 0.f);
                const float4 w4 = ((const float4*)w2t)[o];
                a0 = fmaf(w4.x, hv, a0);
                a1 = fmaf(w4.y, hv, a1);
                a2 = fmaf(w4.z, hv, a2);
                a3 = fmaf(w4.w, hv, a3);
            }
        }
        a0 += __shfl_xor(a0, 16); a0 += __shfl_xor(a0, 32);
        a1 += __shfl_xor(a1, 16); a1 += __shfl_xor(a1, 32);
        a2 += __shfl_xor(a2, 16); a2 += __shfl_xor(a2, 32);
        a3 += __shfl_xor(a3, 16); a3 += __shfl_xor(a3, 32);

        if (lg == 0) {
            // swizzled write: px = j0+l15 -> pxs = (px>>2) + 64*(px&3)
            int pxs = 4 * ch + (l15 >> 2) + 64 * (l15 & 3);
            wlds[0][pxs] = softplus_f(a0 + bb2_0);
            wlds[1][pxs] = softplus_f(a1 + bb2_1);
            wlds[2][pxs] = softplus_f(a2 + bb2_2);
            wlds[3][pxs] = softplus_f(a3 + bb2_3);
        }
    }

    __syncthreads();

    // Lane owns px 4*lane..4*lane+3 of the row; elem e at [d][64*e + lane].
    float4 WU, WD, WL, WR;
    WU.x = wlds[0][lane];       WU.y = wlds[0][64 + lane];
    WU.z = wlds[0][128 + lane]; WU.w = wlds[0][192 + lane];
    WD.x = wlds[1][lane];       WD.y = wlds[1][64 + lane];
    WD.z = wlds[1][128 + lane]; WD.w = wlds[1][192 + lane];
    WL.x = wlds[2][lane];       WL.y = wlds[2][64 + lane];
    WL.z = wlds[2][128 + lane]; WL.w = wlds[2][192 + lane];
    WR.x = wlds[3][lane];       WR.y = wlds[3][64 + lane];
    WR.z = wlds[3][128 + lane]; WR.w = wlds[3][192 + lane];
    float4 WS;
    WS.x = (WU.x + WD.x) + (WL.x + WR.x);
    WS.y = (WU.y + WD.y) + (WL.y + WR.y);
    WS.z = (WU.z + WD.z) + (WL.z + WR.z);
    WS.w = (WU.w + WD.w) + (WL.w + WR.w);

    // ---- phase 3: wave wv streams channels [wv*32, wv*32+32), float4/lane ----
    const int j4 = lane * 4;
    const float* pc = u   + rowoff + j4 + (size_t)(wv * 32) * HWn;
    float*       po = out + rowoff + j4 + (size_t)(wv * 32) * HWn;

    if (hu && hd) {
        #pragma unroll 4
        for (int c = 0; c < 32; ++c) {
            const float* rp = pc + (size_t)c * HWn;
            float4 ctr = *(const float4*)rp;
            float4 up4 = *(const float4*)(rp - Wn);
            float4 dn4 = *(const float4*)(rp + Wn);
            float lw = __shfl(ctr.w, lane - 1);
            float rw = __shfl(ctr.x, lane + 1);
            float lfx = (lane == 0)  ? 0.f : lw;
            float rtw = (lane == 63) ? 0.f : rw;
            float4 r;
            r.x = fmaf(WU.x, up4.x, fmaf(WD.x, dn4.x, fmaf(WL.x, lfx,   fmaf(WR.x, ctr.y, -WS.x * ctr.x))));
            r.y = fmaf(WU.y, up4.y, fmaf(WD.y, dn4.y, fmaf(WL.y, ctr.x, fmaf(WR.y, ctr.z, -WS.y * ctr.y))));
            r.z = fmaf(WU.z, up4.z, fmaf(WD.z, dn4.z, fmaf(WL.z, ctr.y, fmaf(WR.z, ctr.w, -WS.z * ctr.z))));
            r.w = fmaf(WU.w, up4.w, fmaf(WD.w, dn4.w, fmaf(WL.w, ctr.z, fmaf(WR.w, rtw,   -WS.w * ctr.w))));
            *(float4*)(po + (size_t)c * HWn) = r;
        }
    } else {
        const float4 z4 = {0.f, 0.f, 0.f, 0.f};
        #pragma unroll 4
        for (int c = 0; c < 32; ++c) {
            const float* rp = pc + (size_t)c * HWn;
            float4 ctr = *(const float4*)rp;
            float4 up4 = hu ? *(const float4*)(rp - Wn) : z4;
            float4 dn4 = hd ? *(const float4*)(rp + Wn) : z4;
            float lw = __shfl(ctr.w, lane - 1);
            float rw = __shfl(ctr.x, lane + 1);
            float lfx = (lane == 0)  ? 0.f : lw;
            float rtw = (lane == 63) ? 0.f : rw;
            float4 r;
            r.x = fmaf(WU.x, up4.x, fmaf(WD.x, dn4.x, fmaf(WL.x, lfx,   fmaf(WR.x, ctr.y, -WS.x * ctr.x))));
            r.y = fmaf(WU.y, up4.y, fmaf(WD.y, dn4.y, fmaf(WL.y, ctr.x, fmaf(WR.y, ctr.z, -WS.y * ctr.y))));
            r.z = fmaf(WU.z, up4.z, fmaf(WD.z, dn4.z, fmaf(WL.z, ctr.y, fmaf(WR.z, ctr.w, -WS.z * ctr.z))));
            r.w = fmaf(WU.w, up4.w, fmaf(WD.w, dn4.w, fmaf(WL.w, ctr.z, fmaf(WR.w, rtw,   -WS.w * ctr.w))));
            *(float4*)(po + (size_t)c * HWn) = r;
        }
    }
}

extern "C" void kernel_launch(void* const* d_in, const int* in_sizes, int n_in,
                              void* d_out, int out_size, void* d_ws, size_t ws_size,
                              hipStream_t stream) {
    const float* u  = (const float*)d_in[0];
    const float* wi = (const float*)d_in[1];
    const float* w1 = (const float*)d_in[2];
    const float* b1 = (const float*)d_in[3];
    const float* w2 = (const float*)d_in[4];
    const float* b2 = (const float*)d_in[5];
    float* out = (float*)d_out;

    uint4* af  = (uint4*)d_ws;                       // 1024 * 16B = 16 KB
    float* w2t = (float*)((char*)d_ws + 16384);      // 256 * 4B  = 1 KB

    prep<<<5, 256, 0, stream>>>(w1, w2, af, w2t);

    int nblocks = Bn * Hn;                           // 2048 blocks, 1 row each
    fused_lap<<<nblocks, 256, 0, stream>>>(u, wi, af, w2t, b1, b2, out);
}